// Round 2
// baseline (296.673 us; speedup 1.0000x reference)
//
#include <hip/hip_runtime.h>

#define NREL 32

typedef short short8 __attribute__((ext_vector_type(8)));
typedef float f32x4 __attribute__((ext_vector_type(4)));

__device__ inline unsigned short f2bf(float f) {
    union { float f; unsigned u; } u; u.f = f;
    unsigned r = u.u + 0x7FFF + ((u.u >> 16) & 1);   // RNE
    return (unsigned short)(r >> 16);
}

// ---------------------------------------------------------------------------
// ws layout:
//   wtb   [2*32*4096] ushort  bf16 normalized tables, TRANSPOSED: wtb[(dir*32+r)*4096 + o*64 + i]
//   lwT   [4096] float        lin_w transposed
//   cntf  [N] float           # edges with src==n
//   cntb  [N] float           # edges with dst==n
//   hist  [32] int            per-rel edge count
//   fill  [64] int            scatter cursors
//   bstart[64] int            bucket start offsets (padded to 64)
//   cinfo [maxC] int          chunk -> bucket (or -1)
//   sorted[maxC*64] int       edge ids, -1 = pad
// ---------------------------------------------------------------------------

__global__ void count_kernel(const int* __restrict__ src, const int* __restrict__ dst,
                             const int* __restrict__ et,
                             float* __restrict__ cntf, float* __restrict__ cntb,
                             int* __restrict__ hist, int E) {
    __shared__ int lh[NREL];
    if (threadIdx.x < NREL) lh[threadIdx.x] = 0;
    __syncthreads();
    int e = blockIdx.x * blockDim.x + threadIdx.x;
    if (e < E) {
        atomicAdd(&cntf[src[e]], 1.0f);
        atomicAdd(&cntb[dst[e]], 1.0f);
        atomicAdd(&lh[et[e]], 1);
    }
    __syncthreads();
    if (threadIdx.x < NREL && lh[threadIdx.x]) atomicAdd(&hist[threadIdx.x], lh[threadIdx.x]);
}

// 64 blocks: (tab,rel). Normalize fp32 table row, write bf16 TRANSPOSED.
__global__ void norm_kernel(const float* __restrict__ wf, const float* __restrict__ wb,
                            unsigned short* __restrict__ wtb) {
    int rel = blockIdx.x & 31;
    int tab = blockIdx.x >> 5;
    const float* s_ = (tab ? wb : wf) + rel * 4096;
    unsigned short* d_ = wtb + (size_t)blockIdx.x * 4096;
    int tid = threadIdx.x;

    float ssum = 0.f;
    #pragma unroll
    for (int k = 0; k < 16; k += 4) {
        float4 v = *(const float4*)(s_ + tid * 16 + k);
        ssum += v.x * v.x + v.y * v.y + v.z * v.z + v.w * v.w;
    }
    #pragma unroll
    for (int off = 32; off >= 1; off >>= 1) ssum += __shfl_down(ssum, off, 64);

    __shared__ float part[4];
    __shared__ float scale_s;
    if ((tid & 63) == 0) part[tid >> 6] = ssum;
    __syncthreads();
    if (tid == 0) scale_s = 1.0f / (sqrtf(part[0] + part[1] + part[2] + part[3]) + 0.01f);
    __syncthreads();
    float sc = scale_s;
    // source elems k = i*64+o, this thread: i = tid>>2, o in [(tid&3)*16, +16)
    int i = tid >> 2, o0 = (tid & 3) * 16;
    #pragma unroll
    for (int q = 0; q < 4; ++q) {
        float4 v = *(const float4*)(s_ + i * 64 + o0 + q * 4);
        d_[(o0 + q * 4 + 0) * 64 + i] = f2bf(v.x * sc);
        d_[(o0 + q * 4 + 1) * 64 + i] = f2bf(v.y * sc);
        d_[(o0 + q * 4 + 2) * 64 + i] = f2bf(v.z * sc);
        d_[(o0 + q * 4 + 3) * 64 + i] = f2bf(v.w * sc);
    }
}

__global__ void prefix_kernel(const int* __restrict__ hist, int* __restrict__ bstart,
                              int* __restrict__ cinfo, int maxC) {
    __shared__ int off[65];
    int tid = threadIdx.x;
    if (tid == 0) {
        int acc = 0;
        for (int b = 0; b < 64; ++b) {
            off[b] = acc;
            bstart[b] = acc;
            int sz = hist[b & 31];
            acc += ((sz + 63) >> 6) << 6;
        }
        off[64] = acc;
    }
    __syncthreads();
    for (int c = tid; c < maxC; c += blockDim.x) {
        int pos = c * 64;
        if (pos >= off[64]) { cinfo[c] = -1; continue; }
        int lo = 0, hi = 64;
        while (hi - lo > 1) { int mid = (lo + hi) >> 1; if (off[mid] <= pos) lo = mid; else hi = mid; }
        cinfo[c] = lo;
    }
}

__global__ void scatter_kernel(const int* __restrict__ et, int* __restrict__ fill,
                               const int* __restrict__ bstart, int* __restrict__ sorted, int E) {
    int e = blockIdx.x * blockDim.x + threadIdx.x;
    if (e >= E) return;
    int r = et[e];
    int p0 = atomicAdd(&fill[r], 1);
    sorted[bstart[r] + p0] = e;
    int p1 = atomicAdd(&fill[32 + r], 1);
    sorted[bstart[32 + r] + p1] = e;
}

__global__ void transpose_lw(const float* __restrict__ lw, float* __restrict__ lwT) {
    int t = threadIdx.x;
    for (int k = t * 16; k < t * 16 + 16; ++k) {
        int o = k & 63, i = k >> 6;
        lwT[k] = lw[o * 64 + i];
    }
}

__global__ void linear_kernel(const float* __restrict__ x, const float* __restrict__ lwT,
                              const float* __restrict__ lb, float* __restrict__ out, int N) {
    __shared__ float xs[4][64];
    int lane = threadIdx.x & 63;
    int wslot = threadIdx.x >> 6;
    int n = blockIdx.x * 4 + wslot;
    bool valid = (n < N);
    int nn = valid ? n : 0;
    xs[wslot][lane] = x[nn * 64 + lane];
    __syncthreads();
    float acc = lb[lane];
    #pragma unroll
    for (int i = 0; i < 64; i += 4) {
        float4 xi = *(const float4*)(&xs[wslot][i]);
        acc = fmaf(xi.x, lwT[(i + 0) * 64 + lane], acc);
        acc = fmaf(xi.y, lwT[(i + 1) * 64 + lane], acc);
        acc = fmaf(xi.z, lwT[(i + 2) * 64 + lane], acc);
        acc = fmaf(xi.w, lwT[(i + 3) * 64 + lane], acc);
    }
    if (valid) out[n * 64 + lane] = acc;
}

// One block per 64-edge chunk of a single (dir,rel) bucket.
// OUT[j][o] = sum_i (x[s_j][i]/deg_j) * Wn[i][o], via mfma_f32_16x16x32_bf16.
#define APITCH 72  // 64 + 8 shorts pad -> stride 144 B, kills the 16-way conflict
__global__ __launch_bounds__(256) void conv_mfma(
        const float* __restrict__ x,
        const int* __restrict__ src, const int* __restrict__ dst,
        const float* __restrict__ cntf, const float* __restrict__ cntb,
        const unsigned short* __restrict__ wtb,
        const int* __restrict__ cinfo, const int* __restrict__ sorted,
        float* __restrict__ out) {
    int info = cinfo[blockIdx.x];
    if (info < 0) return;
    int rel = info & 31, dir = info >> 5;

    __shared__ unsigned short As[64 * APITCH];  // As[j][i] = bf16(x[s_j][i]*inv)
    __shared__ unsigned short Bs[64 * APITCH];  // Bs[o][i] = Wn[i][o]
    __shared__ int dstS[64];

    int tid = threadIdx.x;
    int j = tid >> 2, part = tid & 3;

    // stage B (transposed table is a straight copy)
    {
        const uint4* s4 = (const uint4*)(wtb + (size_t)((dir << 5) + rel) * 4096 + j * 64 + part * 16);
        uint4 v0 = s4[0], v1 = s4[1];
        *(uint4*)(&Bs[j * APITCH + part * 16]) = v0;
        *(uint4*)(&Bs[j * APITCH + part * 16 + 8]) = v1;
    }

    // stage A
    int e = sorted[blockIdx.x * 64 + j];
    if (e < 0) {
        uint4 z = {0, 0, 0, 0};
        *(uint4*)(&As[j * APITCH + part * 16]) = z;
        *(uint4*)(&As[j * APITCH + part * 16 + 8]) = z;
        if (part == 0) dstS[j] = -1;
    } else {
        int s_ = dir ? dst[e] : src[e];
        int d_ = dir ? src[e] : dst[e];
        float cv = dir ? cntb[s_] : cntf[s_];
        float inv = 1.0f / (cv + 1.0f);
        const float4* xr = (const float4*)(x + (size_t)s_ * 64 + part * 16);
        float4 v0 = xr[0], v1 = xr[1], v2 = xr[2], v3 = xr[3];
        uint4 r0, r1;
        r0.x = f2bf(v0.x * inv) | ((unsigned)f2bf(v0.y * inv) << 16);
        r0.y = f2bf(v0.z * inv) | ((unsigned)f2bf(v0.w * inv) << 16);
        r0.z = f2bf(v1.x * inv) | ((unsigned)f2bf(v1.y * inv) << 16);
        r0.w = f2bf(v1.z * inv) | ((unsigned)f2bf(v1.w * inv) << 16);
        r1.x = f2bf(v2.x * inv) | ((unsigned)f2bf(v2.y * inv) << 16);
        r1.y = f2bf(v2.z * inv) | ((unsigned)f2bf(v2.w * inv) << 16);
        r1.z = f2bf(v3.x * inv) | ((unsigned)f2bf(v3.y * inv) << 16);
        r1.w = f2bf(v3.z * inv) | ((unsigned)f2bf(v3.w * inv) << 16);
        *(uint4*)(&As[j * APITCH + part * 16]) = r0;
        *(uint4*)(&As[j * APITCH + part * 16 + 8]) = r1;
        if (part == 0) dstS[j] = d_;
    }
    __syncthreads();

    // MFMA: wave w computes edge rows [16w,16w+16) x all 64 out channels
    int lane = tid & 63, w = tid >> 6;
    int m = lane & 15, quad = lane >> 4;
    f32x4 acc0 = {0.f, 0.f, 0.f, 0.f}, acc1 = acc0, acc2 = acc0, acc3 = acc0;
    #pragma unroll
    for (int k0 = 0; k0 < 64; k0 += 32) {
        short8 a  = *(const short8*)(&As[(w * 16 + m) * APITCH + k0 + quad * 8]);
        short8 b0 = *(const short8*)(&Bs[(0  + m) * APITCH + k0 + quad * 8]);
        short8 b1 = *(const short8*)(&Bs[(16 + m) * APITCH + k0 + quad * 8]);
        short8 b2 = *(const short8*)(&Bs[(32 + m) * APITCH + k0 + quad * 8]);
        short8 b3 = *(const short8*)(&Bs[(48 + m) * APITCH + k0 + quad * 8]);
        acc0 = __builtin_amdgcn_mfma_f32_16x16x32_bf16(a, b0, acc0, 0, 0, 0);
        acc1 = __builtin_amdgcn_mfma_f32_16x16x32_bf16(a, b1, acc1, 0, 0, 0);
        acc2 = __builtin_amdgcn_mfma_f32_16x16x32_bf16(a, b2, acc2, 0, 0, 0);
        acc3 = __builtin_amdgcn_mfma_f32_16x16x32_bf16(a, b3, acc3, 0, 0, 0);
    }

    // epilogue: C/D layout col=lane&15, row=quad*4+reg (m89-verified)
    int row_base = w * 16 + quad * 4;
    #pragma unroll
    for (int r = 0; r < 4; ++r) {
        int d_ = dstS[row_base + r];
        if (d_ >= 0) {
            float* op = out + (size_t)d_ * 64 + m;
            atomicAdd(op +  0, acc0[r]);
            atomicAdd(op + 16, acc1[r]);
            atomicAdd(op + 32, acc2[r]);
            atomicAdd(op + 48, acc3[r]);
        }
    }
}

extern "C" void kernel_launch(void* const* d_in, const int* in_sizes, int n_in,
                              void* d_out, int out_size, void* d_ws, size_t ws_size,
                              hipStream_t stream) {
    const float* x  = (const float*)d_in[0];
    const int*   ei = (const int*)  d_in[1];
    const int*   et = (const int*)  d_in[2];
    const float* wf = (const float*)d_in[3];
    const float* wb = (const float*)d_in[4];
    const float* lw = (const float*)d_in[5];
    const float* lb = (const float*)d_in[6];
    float* out = (float*)d_out;

    const int E = in_sizes[2];
    const int N = in_sizes[0] / 64;
    const int maxC = ((2 * E + 63) >> 6) + 64;

    char* p = (char*)d_ws;
    unsigned short* wtb = (unsigned short*)p;  p += (size_t)2 * NREL * 4096 * sizeof(unsigned short);
    float* lwT  = (float*)p;                   p += 4096 * sizeof(float);
    float* cntf = (float*)p;                   p += (size_t)N * sizeof(float);
    float* cntb = (float*)p;                   p += (size_t)N * sizeof(float);
    int*   hist = (int*)p;                     p += NREL * sizeof(int);
    int*   fill = (int*)p;                     p += 64 * sizeof(int);
    int*   bst  = (int*)p;                     p += 64 * sizeof(int);
    int*   cinfo = (int*)p;                    p += (size_t)maxC * sizeof(int);
    int*   sorted = (int*)p;                   p += (size_t)maxC * 64 * sizeof(int);

    const int* srcp = ei;
    const int* dstp = ei + E;

    // zero: cntf, cntb, hist, fill (contiguous)
    hipMemsetAsync(cntf, 0, ((size_t)2 * N + NREL + 64) * sizeof(float), stream);
    // pad marker for sorted
    hipMemsetAsync(sorted, 0xFF, (size_t)maxC * 64 * sizeof(int), stream);

    count_kernel<<<(E + 255) / 256, 256, 0, stream>>>(srcp, dstp, et, cntf, cntb, hist, E);
    prefix_kernel<<<1, 256, 0, stream>>>(hist, bst, cinfo, maxC);
    scatter_kernel<<<(E + 255) / 256, 256, 0, stream>>>(et, fill, bst, sorted, E);
    norm_kernel<<<64, 256, 0, stream>>>(wf, wb, wtb);
    transpose_lw<<<1, 256, 0, stream>>>(lw, lwT);
    linear_kernel<<<(N + 3) / 4, 256, 0, stream>>>(x, lwT, lb, out, N);
    conv_mfma<<<maxC, 256, 0, stream>>>(x, srcp, dstp, cntf, cntb, wtb, cinfo, sorted, out);
}

// Round 3
// 134.944 us; speedup vs baseline: 2.1985x; 2.1985x over previous
//
#include <hip/hip_runtime.h>

#define NREL 32

typedef short short8 __attribute__((ext_vector_type(8)));
typedef float f32x4 __attribute__((ext_vector_type(4)));

__device__ inline unsigned short f2bf(float f) {
    union { float f; unsigned u; } u; u.f = f;
    unsigned r = u.u + 0x7FFF + ((u.u >> 16) & 1);   // RNE
    return (unsigned short)(r >> 16);
}

// ---------------------------------------------------------------------------
// ws layout:
//   wtb   [2*32*4096] ushort  bf16 normalized tables, TRANSPOSED: wtb[(dir*32+r)*4096 + o*64 + i]
//   lwT   [4096] float        lin_w transposed
//   cntf  [N] float           # edges with src==n
//   cntb  [N] float           # edges with dst==n
//   hist  [32] int            per-rel edge count
//   fill  [32] int            scatter cursors
//   bstart[32] int            bucket start offsets (padded to 64)
//   cinfo [maxC] int          chunk -> rel (or -1)
//   sorted[maxC*64] int       edge ids, -1 = pad  (shared by both directions)
// ---------------------------------------------------------------------------

__global__ void count_kernel(const int* __restrict__ src, const int* __restrict__ dst,
                             const int* __restrict__ et,
                             float* __restrict__ cntf, float* __restrict__ cntb,
                             int* __restrict__ hist, int E) {
    __shared__ int lh[NREL];
    if (threadIdx.x < NREL) lh[threadIdx.x] = 0;
    __syncthreads();
    int e = blockIdx.x * blockDim.x + threadIdx.x;
    if (e < E) {
        atomicAdd(&cntf[src[e]], 1.0f);
        atomicAdd(&cntb[dst[e]], 1.0f);
        atomicAdd(&lh[et[e]], 1);
    }
    __syncthreads();
    if (threadIdx.x < NREL && lh[threadIdx.x]) atomicAdd(&hist[threadIdx.x], lh[threadIdx.x]);
}

// 64 blocks: (tab,rel). Normalize fp32 table row, write bf16 TRANSPOSED.
__global__ void norm_kernel(const float* __restrict__ wf, const float* __restrict__ wb,
                            unsigned short* __restrict__ wtb) {
    int rel = blockIdx.x & 31;
    int tab = blockIdx.x >> 5;
    const float* s_ = (tab ? wb : wf) + rel * 4096;
    unsigned short* d_ = wtb + (size_t)blockIdx.x * 4096;
    int tid = threadIdx.x;

    float ssum = 0.f;
    #pragma unroll
    for (int k = 0; k < 16; k += 4) {
        float4 v = *(const float4*)(s_ + tid * 16 + k);
        ssum += v.x * v.x + v.y * v.y + v.z * v.z + v.w * v.w;
    }
    #pragma unroll
    for (int off = 32; off >= 1; off >>= 1) ssum += __shfl_down(ssum, off, 64);

    __shared__ float part[4];
    __shared__ float scale_s;
    if ((tid & 63) == 0) part[tid >> 6] = ssum;
    __syncthreads();
    if (tid == 0) scale_s = 1.0f / (sqrtf(part[0] + part[1] + part[2] + part[3]) + 0.01f);
    __syncthreads();
    float sc = scale_s;
    // source elems k = i*64+o, this thread: i = tid>>2, o in [(tid&3)*16, +16)
    int i = tid >> 2, o0 = (tid & 3) * 16;
    #pragma unroll
    for (int q = 0; q < 4; ++q) {
        float4 v = *(const float4*)(s_ + i * 64 + o0 + q * 4);
        d_[(o0 + q * 4 + 0) * 64 + i] = f2bf(v.x * sc);
        d_[(o0 + q * 4 + 1) * 64 + i] = f2bf(v.y * sc);
        d_[(o0 + q * 4 + 2) * 64 + i] = f2bf(v.z * sc);
        d_[(o0 + q * 4 + 3) * 64 + i] = f2bf(v.w * sc);
    }
}

__global__ void prefix_kernel(const int* __restrict__ hist, int* __restrict__ bstart,
                              int* __restrict__ cinfo, int maxC) {
    __shared__ int off[NREL + 1];
    int tid = threadIdx.x;
    if (tid == 0) {
        int acc = 0;
        for (int b = 0; b < NREL; ++b) {
            off[b] = acc;
            bstart[b] = acc;
            acc += ((hist[b] + 63) >> 6) << 6;
        }
        off[NREL] = acc;
    }
    __syncthreads();
    for (int c = tid; c < maxC; c += blockDim.x) {
        int pos = c * 64;
        if (pos >= off[NREL]) { cinfo[c] = -1; continue; }
        int lo = 0, hi = NREL;
        while (hi - lo > 1) { int mid = (lo + hi) >> 1; if (off[mid] <= pos) lo = mid; else hi = mid; }
        cinfo[c] = lo;
    }
}

// Block-aggregated scatter: LDS histogram -> one global atomic per (block,rel)
// -> conflict-free global writes. (Round-2's per-thread global atomics on 64
// counters cost 163 us of pure same-address serialization.)
__global__ void scatter_kernel(const int* __restrict__ et, int* __restrict__ fill,
                               const int* __restrict__ bstart, int* __restrict__ sorted, int E) {
    __shared__ int lh[NREL];
    __shared__ int lbase[NREL];
    int tid = threadIdx.x;
    if (tid < NREL) lh[tid] = 0;
    __syncthreads();
    int e = blockIdx.x * blockDim.x + tid;
    int r = 0, my = 0;
    bool valid = (e < E);
    if (valid) { r = et[e]; my = atomicAdd(&lh[r], 1); }
    __syncthreads();
    if (tid < NREL && lh[tid]) lbase[tid] = atomicAdd(&fill[tid], lh[tid]);
    __syncthreads();
    if (valid) sorted[bstart[r] + lbase[r] + my] = e;
}

__global__ void transpose_lw(const float* __restrict__ lw, float* __restrict__ lwT) {
    int t = threadIdx.x;
    for (int k = t * 16; k < t * 16 + 16; ++k) {
        int o = k & 63, i = k >> 6;
        lwT[k] = lw[o * 64 + i];
    }
}

__global__ void linear_kernel(const float* __restrict__ x, const float* __restrict__ lwT,
                              const float* __restrict__ lb, float* __restrict__ out, int N) {
    __shared__ float xs[4][64];
    int lane = threadIdx.x & 63;
    int wslot = threadIdx.x >> 6;
    int n = blockIdx.x * 4 + wslot;
    bool valid = (n < N);
    int nn = valid ? n : 0;
    xs[wslot][lane] = x[nn * 64 + lane];
    __syncthreads();
    float acc = lb[lane];
    #pragma unroll
    for (int i = 0; i < 64; i += 4) {
        float4 xi = *(const float4*)(&xs[wslot][i]);
        acc = fmaf(xi.x, lwT[(i + 0) * 64 + lane], acc);
        acc = fmaf(xi.y, lwT[(i + 1) * 64 + lane], acc);
        acc = fmaf(xi.z, lwT[(i + 2) * 64 + lane], acc);
        acc = fmaf(xi.w, lwT[(i + 3) * 64 + lane], acc);
    }
    if (valid) out[n * 64 + lane] = acc;
}

// One block per (64-edge chunk of a rel bucket) x (direction = blockIdx.y).
// OUT[j][o] = sum_i (x[s_j][i]/deg_j) * Wn[i][o], via mfma_f32_16x16x32_bf16.
#define APITCH 72  // 64 + 8 shorts pad -> stride 144 B, kills the 16-way conflict
__global__ __launch_bounds__(256) void conv_mfma(
        const float* __restrict__ x,
        const int* __restrict__ src, const int* __restrict__ dst,
        const float* __restrict__ cntf, const float* __restrict__ cntb,
        const unsigned short* __restrict__ wtb,
        const int* __restrict__ cinfo, const int* __restrict__ sorted,
        float* __restrict__ out) {
    int rel = cinfo[blockIdx.x];
    if (rel < 0) return;
    int dir = blockIdx.y;

    __shared__ unsigned short As[64 * APITCH];  // As[j][i] = bf16(x[s_j][i]*inv)
    __shared__ unsigned short Bs[64 * APITCH];  // Bs[o][i] = Wn[i][o]
    __shared__ int dstS[64];

    int tid = threadIdx.x;
    int j = tid >> 2, part = tid & 3;

    // stage B (transposed table is a straight copy)
    {
        const uint4* s4 = (const uint4*)(wtb + (size_t)((dir << 5) + rel) * 4096 + j * 64 + part * 16);
        uint4 v0 = s4[0], v1 = s4[1];
        *(uint4*)(&Bs[j * APITCH + part * 16]) = v0;
        *(uint4*)(&Bs[j * APITCH + part * 16 + 8]) = v1;
    }

    // stage A
    int e = sorted[blockIdx.x * 64 + j];
    if (e < 0) {
        uint4 z = {0, 0, 0, 0};
        *(uint4*)(&As[j * APITCH + part * 16]) = z;
        *(uint4*)(&As[j * APITCH + part * 16 + 8]) = z;
        if (part == 0) dstS[j] = -1;
    } else {
        int s_ = dir ? dst[e] : src[e];
        int d_ = dir ? src[e] : dst[e];
        float cv = dir ? cntb[s_] : cntf[s_];
        float inv = 1.0f / (cv + 1.0f);
        const float4* xr = (const float4*)(x + (size_t)s_ * 64 + part * 16);
        float4 v0 = xr[0], v1 = xr[1], v2 = xr[2], v3 = xr[3];
        uint4 r0, r1;
        r0.x = f2bf(v0.x * inv) | ((unsigned)f2bf(v0.y * inv) << 16);
        r0.y = f2bf(v0.z * inv) | ((unsigned)f2bf(v0.w * inv) << 16);
        r0.z = f2bf(v1.x * inv) | ((unsigned)f2bf(v1.y * inv) << 16);
        r0.w = f2bf(v1.z * inv) | ((unsigned)f2bf(v1.w * inv) << 16);
        r1.x = f2bf(v2.x * inv) | ((unsigned)f2bf(v2.y * inv) << 16);
        r1.y = f2bf(v2.z * inv) | ((unsigned)f2bf(v2.w * inv) << 16);
        r1.z = f2bf(v3.x * inv) | ((unsigned)f2bf(v3.y * inv) << 16);
        r1.w = f2bf(v3.z * inv) | ((unsigned)f2bf(v3.w * inv) << 16);
        *(uint4*)(&As[j * APITCH + part * 16]) = r0;
        *(uint4*)(&As[j * APITCH + part * 16 + 8]) = r1;
        if (part == 0) dstS[j] = d_;
    }
    __syncthreads();

    // MFMA: wave w computes edge rows [16w,16w+16) x all 64 out channels
    int lane = tid & 63, w = tid >> 6;
    int m = lane & 15, quad = lane >> 4;
    f32x4 acc0 = {0.f, 0.f, 0.f, 0.f}, acc1 = acc0, acc2 = acc0, acc3 = acc0;
    #pragma unroll
    for (int k0 = 0; k0 < 64; k0 += 32) {
        short8 a  = *(const short8*)(&As[(w * 16 + m) * APITCH + k0 + quad * 8]);
        short8 b0 = *(const short8*)(&Bs[(0  + m) * APITCH + k0 + quad * 8]);
        short8 b1 = *(const short8*)(&Bs[(16 + m) * APITCH + k0 + quad * 8]);
        short8 b2 = *(const short8*)(&Bs[(32 + m) * APITCH + k0 + quad * 8]);
        short8 b3 = *(const short8*)(&Bs[(48 + m) * APITCH + k0 + quad * 8]);
        acc0 = __builtin_amdgcn_mfma_f32_16x16x32_bf16(a, b0, acc0, 0, 0, 0);
        acc1 = __builtin_amdgcn_mfma_f32_16x16x32_bf16(a, b1, acc1, 0, 0, 0);
        acc2 = __builtin_amdgcn_mfma_f32_16x16x32_bf16(a, b2, acc2, 0, 0, 0);
        acc3 = __builtin_amdgcn_mfma_f32_16x16x32_bf16(a, b3, acc3, 0, 0, 0);
    }

    // epilogue: C/D layout col=lane&15, row=quad*4+reg (m89-verified)
    int row_base = w * 16 + quad * 4;
    #pragma unroll
    for (int r = 0; r < 4; ++r) {
        int d_ = dstS[row_base + r];
        if (d_ >= 0) {
            float* op = out + (size_t)d_ * 64 + m;
            atomicAdd(op +  0, acc0[r]);
            atomicAdd(op + 16, acc1[r]);
            atomicAdd(op + 32, acc2[r]);
            atomicAdd(op + 48, acc3[r]);
        }
    }
}

extern "C" void kernel_launch(void* const* d_in, const int* in_sizes, int n_in,
                              void* d_out, int out_size, void* d_ws, size_t ws_size,
                              hipStream_t stream) {
    const float* x  = (const float*)d_in[0];
    const int*   ei = (const int*)  d_in[1];
    const int*   et = (const int*)  d_in[2];
    const float* wf = (const float*)d_in[3];
    const float* wb = (const float*)d_in[4];
    const float* lw = (const float*)d_in[5];
    const float* lb = (const float*)d_in[6];
    float* out = (float*)d_out;

    const int E = in_sizes[2];
    const int N = in_sizes[0] / 64;
    const int maxC = ((E + 63) >> 6) + NREL;   // one shared sort for both dirs

    char* p = (char*)d_ws;
    unsigned short* wtb = (unsigned short*)p;  p += (size_t)2 * NREL * 4096 * sizeof(unsigned short);
    float* lwT  = (float*)p;                   p += 4096 * sizeof(float);
    float* cntf = (float*)p;                   p += (size_t)N * sizeof(float);
    float* cntb = (float*)p;                   p += (size_t)N * sizeof(float);
    int*   hist = (int*)p;                     p += NREL * sizeof(int);
    int*   fill = (int*)p;                     p += NREL * sizeof(int);
    int*   bst  = (int*)p;                     p += NREL * sizeof(int);
    int*   cinfo = (int*)p;                    p += (size_t)maxC * sizeof(int);
    int*   sorted = (int*)p;                   p += (size_t)maxC * 64 * sizeof(int);

    const int* srcp = ei;
    const int* dstp = ei + E;

    // zero: cntf, cntb, hist, fill (contiguous)
    hipMemsetAsync(cntf, 0, ((size_t)2 * N + 2 * NREL) * sizeof(float), stream);
    // pad marker for sorted
    hipMemsetAsync(sorted, 0xFF, (size_t)maxC * 64 * sizeof(int), stream);

    count_kernel<<<(E + 255) / 256, 256, 0, stream>>>(srcp, dstp, et, cntf, cntb, hist, E);
    prefix_kernel<<<1, 256, 0, stream>>>(hist, bst, cinfo, maxC);
    scatter_kernel<<<(E + 255) / 256, 256, 0, stream>>>(et, fill, bst, sorted, E);
    norm_kernel<<<64, 256, 0, stream>>>(wf, wb, wtb);
    transpose_lw<<<1, 256, 0, stream>>>(lw, lwT);
    linear_kernel<<<(N + 3) / 4, 256, 0, stream>>>(x, lwT, lb, out, N);
    dim3 cgrid(maxC, 2);
    conv_mfma<<<cgrid, 256, 0, stream>>>(x, srcp, dstp, cntf, cntb, wtb, cinfo, sorted, out);
}

// Round 4
// 115.197 us; speedup vs baseline: 2.5754x; 1.1714x over previous
//
#include <hip/hip_runtime.h>

#define NREL 32

typedef short short8 __attribute__((ext_vector_type(8)));
typedef float f32x4 __attribute__((ext_vector_type(4)));

__device__ inline unsigned short f2bf(float f) {
    union { float f; unsigned u; } u; u.f = f;
    unsigned r = u.u + 0x7FFF + ((u.u >> 16) & 1);   // RNE
    return (unsigned short)(r >> 16);
}

// Padded-bucket exclusive scan over hist[32], in-register (lanes 0..31 valid).
// Returns via refs: h (hist[lane]), excl (padded exclusive prefix).
__device__ inline void bucket_scan(const int* __restrict__ hist, int lane,
                                   int& h, int& P, int& excl) {
    h = (lane < NREL) ? hist[lane] : 0;
    P = ((h + 63) >> 6) << 6;
    int s = P;
    #pragma unroll
    for (int off = 1; off < 32; off <<= 1) {
        int t = __shfl_up(s, off, 64);
        if ((lane & 31) >= off) s += t;
    }
    excl = s - P;
}

// ---------------------------------------------------------------------------
// ws layout:
//   wtb   [2*32*4096] ushort  bf16 normalized tables, TRANSPOSED:
//                             wtb[(dir*32+r)*4096 + o*64 + i]
//   cntf  [N] float           # edges with src==n
//   cntb  [N] float           # edges with dst==n
//   hist  [32] int            per-rel edge count
//   fill  [32] int            scatter cursors
//   sorted[maxC*64] int       edge ids grouped by rel (pad slots never read)
// ---------------------------------------------------------------------------

// Fused independent setup: blocks [0,nCountB) count degrees+hist,
// [nCountB,nCountB+64) normalize+transpose weights, rest do x@lin_w^T+b.
__global__ __launch_bounds__(256) void setup_kernel(
        const float* __restrict__ x,
        const int* __restrict__ src, const int* __restrict__ dst,
        const int* __restrict__ et,
        const float* __restrict__ wf, const float* __restrict__ wb,
        const float* __restrict__ lw, const float* __restrict__ lb,
        float* __restrict__ cntf, float* __restrict__ cntb,
        int* __restrict__ hist, unsigned short* __restrict__ wtb,
        float* __restrict__ out, int E, int N, int nCountB) {
    __shared__ float smem[4 * 8 * 64 + 8];   // linear xs / norm part / count lh
    int tid = threadIdx.x;
    int b = blockIdx.x;

    if (b < nCountB) {
        // ---- count role ----
        int* lh = (int*)smem;
        if (tid < NREL) lh[tid] = 0;
        __syncthreads();
        int e = b * 256 + tid;
        if (e < E) {
            atomicAdd(&cntf[src[e]], 1.0f);
            atomicAdd(&cntb[dst[e]], 1.0f);
            atomicAdd(&lh[et[e]], 1);
        }
        __syncthreads();
        if (tid < NREL && lh[tid]) atomicAdd(&hist[tid], lh[tid]);
        return;
    }
    b -= nCountB;
    if (b < 64) {
        // ---- norm role: normalize fp32 table row, write bf16 transposed ----
        int rel = b & 31, tab = b >> 5;
        const float* s_ = (tab ? wb : wf) + rel * 4096;
        unsigned short* d_ = wtb + (size_t)b * 4096;
        float* part = smem;
        float ssum = 0.f;
        #pragma unroll
        for (int k = 0; k < 16; k += 4) {
            float4 v = *(const float4*)(s_ + tid * 16 + k);
            ssum += v.x * v.x + v.y * v.y + v.z * v.z + v.w * v.w;
        }
        #pragma unroll
        for (int off = 32; off >= 1; off >>= 1) ssum += __shfl_down(ssum, off, 64);
        if ((tid & 63) == 0) part[tid >> 6] = ssum;
        __syncthreads();
        if (tid == 0) part[4] = 1.0f / (sqrtf(part[0] + part[1] + part[2] + part[3]) + 0.01f);
        __syncthreads();
        float sc = part[4];
        int i = tid >> 2, o0 = (tid & 3) * 16;
        #pragma unroll
        for (int q = 0; q < 4; ++q) {
            float4 v = *(const float4*)(s_ + i * 64 + o0 + q * 4);
            d_[(o0 + q * 4 + 0) * 64 + i] = f2bf(v.x * sc);
            d_[(o0 + q * 4 + 1) * 64 + i] = f2bf(v.y * sc);
            d_[(o0 + q * 4 + 2) * 64 + i] = f2bf(v.z * sc);
            d_[(o0 + q * 4 + 3) * 64 + i] = f2bf(v.w * sc);
        }
        return;
    }
    b -= 64;
    // ---- linear role: 32 nodes/block, lane o keeps lw row o in 16 float4s ----
    {
        int lane = tid & 63, w = tid >> 6;
        int nodeBase = b * 32 + w * 8;
        float4 wrow[16];
        const float4* lwrow = (const float4*)(lw + lane * 64);
        #pragma unroll
        for (int g = 0; g < 16; ++g) wrow[g] = lwrow[g];
        float bias = lb[lane];
        float* xs = smem + w * 8 * 64;
        #pragma unroll
        for (int t = 0; t < 8; ++t) {
            int n = nodeBase + t;
            if (n < N) xs[t * 64 + lane] = x[(size_t)n * 64 + lane];
        }
        __syncthreads();
        for (int t = 0; t < 8; ++t) {
            int n = nodeBase + t;
            if (n >= N) break;
            float acc = bias;
            const float4* xr = (const float4*)(xs + t * 64);
            #pragma unroll
            for (int g = 0; g < 16; ++g) {
                float4 xv = xr[g];   // LDS broadcast read
                acc = fmaf(xv.x, wrow[g].x, acc);
                acc = fmaf(xv.y, wrow[g].y, acc);
                acc = fmaf(xv.z, wrow[g].z, acc);
                acc = fmaf(xv.w, wrow[g].w, acc);
            }
            out[(size_t)n * 64 + lane] = acc;
        }
    }
}

// Block-aggregated counting-sort scatter into rel buckets.
__global__ void scatter_kernel(const int* __restrict__ et, int* __restrict__ fill,
                               const int* __restrict__ hist, int* __restrict__ sorted, int E) {
    __shared__ int lh[NREL];
    __shared__ int lbase[NREL];
    __shared__ int bstartS[NREL];
    int tid = threadIdx.x;
    if (tid < 64) {
        int h, P, excl;
        bucket_scan(hist, tid, h, P, excl);
        if (tid < NREL) bstartS[tid] = excl;
    }
    if (tid < NREL) lh[tid] = 0;
    __syncthreads();
    int e = blockIdx.x * blockDim.x + tid;
    int r = 0, my = 0;
    bool valid = (e < E);
    if (valid) { r = et[e]; my = atomicAdd(&lh[r], 1); }
    __syncthreads();
    if (tid < NREL && lh[tid]) lbase[tid] = atomicAdd(&fill[tid], lh[tid]);
    __syncthreads();
    if (valid) sorted[bstartS[r] + lbase[r] + my] = e;
}

// One block per (64-edge chunk) x (direction = blockIdx.y). Bucket located
// in-register from hist — no cinfo array, no sentinel memset.
#define APITCH 72  // 64 + 8 shorts pad
__global__ __launch_bounds__(256) void conv_mfma(
        const float* __restrict__ x,
        const int* __restrict__ src, const int* __restrict__ dst,
        const float* __restrict__ cntf, const float* __restrict__ cntb,
        const int* __restrict__ hist,
        const unsigned short* __restrict__ wtb,
        const int* __restrict__ sorted,
        float* __restrict__ out) {
    int tid = threadIdx.x;
    int lane = tid & 63;
    int h, P, excl;
    bucket_scan(hist, lane, h, P, excl);
    int pos = blockIdx.x * 64;
    unsigned long long m_ = __ballot(lane < NREL && pos >= excl && pos < excl + P);
    if (m_ == 0) return;                     // past last chunk (uniform)
    int rel = __ffsll(m_) - 1;
    int start = __shfl(excl, rel, 64);
    int hr = __shfl(h, rel, 64);
    int valid = hr - (pos - start);
    if (valid > 64) valid = 64;
    int dir = blockIdx.y;

    __shared__ unsigned short As[64 * APITCH];  // As[j][i] = bf16(x[s_j][i]*inv)
    __shared__ unsigned short Bs[64 * APITCH];  // Bs[o][i] = Wn[i][o]
    __shared__ int dstS[64];

    int j = tid >> 2, part = tid & 3;

    // stage B (transposed table is a straight copy)
    {
        const uint4* s4 = (const uint4*)(wtb + (size_t)((dir << 5) + rel) * 4096 + j * 64 + part * 16);
        uint4 v0 = s4[0], v1 = s4[1];
        *(uint4*)(&Bs[j * APITCH + part * 16]) = v0;
        *(uint4*)(&Bs[j * APITCH + part * 16 + 8]) = v1;
    }

    // stage A
    if (j >= valid) {
        uint4 z = {0, 0, 0, 0};
        *(uint4*)(&As[j * APITCH + part * 16]) = z;
        *(uint4*)(&As[j * APITCH + part * 16 + 8]) = z;
        if (part == 0) dstS[j] = -1;
    } else {
        int e = sorted[pos + j];
        int s_ = dir ? dst[e] : src[e];
        int d_ = dir ? src[e] : dst[e];
        float cv = dir ? cntb[s_] : cntf[s_];
        float inv = 1.0f / (cv + 1.0f);
        const float4* xr = (const float4*)(x + (size_t)s_ * 64 + part * 16);
        float4 v0 = xr[0], v1 = xr[1], v2 = xr[2], v3 = xr[3];
        uint4 r0, r1;
        r0.x = f2bf(v0.x * inv) | ((unsigned)f2bf(v0.y * inv) << 16);
        r0.y = f2bf(v0.z * inv) | ((unsigned)f2bf(v0.w * inv) << 16);
        r0.z = f2bf(v1.x * inv) | ((unsigned)f2bf(v1.y * inv) << 16);
        r0.w = f2bf(v1.z * inv) | ((unsigned)f2bf(v1.w * inv) << 16);
        r1.x = f2bf(v2.x * inv) | ((unsigned)f2bf(v2.y * inv) << 16);
        r1.y = f2bf(v2.z * inv) | ((unsigned)f2bf(v2.w * inv) << 16);
        r1.z = f2bf(v3.x * inv) | ((unsigned)f2bf(v3.y * inv) << 16);
        r1.w = f2bf(v3.z * inv) | ((unsigned)f2bf(v3.w * inv) << 16);
        *(uint4*)(&As[j * APITCH + part * 16]) = r0;
        *(uint4*)(&As[j * APITCH + part * 16 + 8]) = r1;
        if (part == 0) dstS[j] = d_;
    }
    __syncthreads();

    // MFMA: wave w computes edge rows [16w,16w+16) x all 64 out channels
    int w = tid >> 6;
    int m = lane & 15, quad = lane >> 4;
    f32x4 acc0 = {0.f, 0.f, 0.f, 0.f}, acc1 = acc0, acc2 = acc0, acc3 = acc0;
    #pragma unroll
    for (int k0 = 0; k0 < 64; k0 += 32) {
        short8 a  = *(const short8*)(&As[(w * 16 + m) * APITCH + k0 + quad * 8]);
        short8 b0 = *(const short8*)(&Bs[(0  + m) * APITCH + k0 + quad * 8]);
        short8 b1 = *(const short8*)(&Bs[(16 + m) * APITCH + k0 + quad * 8]);
        short8 b2 = *(const short8*)(&Bs[(32 + m) * APITCH + k0 + quad * 8]);
        short8 b3 = *(const short8*)(&Bs[(48 + m) * APITCH + k0 + quad * 8]);
        acc0 = __builtin_amdgcn_mfma_f32_16x16x32_bf16(a, b0, acc0, 0, 0, 0);
        acc1 = __builtin_amdgcn_mfma_f32_16x16x32_bf16(a, b1, acc1, 0, 0, 0);
        acc2 = __builtin_amdgcn_mfma_f32_16x16x32_bf16(a, b2, acc2, 0, 0, 0);
        acc3 = __builtin_amdgcn_mfma_f32_16x16x32_bf16(a, b3, acc3, 0, 0, 0);
    }

    // epilogue: C/D layout col=lane&15, row=quad*4+reg (m89-verified)
    int row_base = w * 16 + quad * 4;
    #pragma unroll
    for (int r = 0; r < 4; ++r) {
        int d_ = dstS[row_base + r];
        if (d_ >= 0) {
            float* op = out + (size_t)d_ * 64 + m;
            atomicAdd(op +  0, acc0[r]);
            atomicAdd(op + 16, acc1[r]);
            atomicAdd(op + 32, acc2[r]);
            atomicAdd(op + 48, acc3[r]);
        }
    }
}

extern "C" void kernel_launch(void* const* d_in, const int* in_sizes, int n_in,
                              void* d_out, int out_size, void* d_ws, size_t ws_size,
                              hipStream_t stream) {
    const float* x  = (const float*)d_in[0];
    const int*   ei = (const int*)  d_in[1];
    const int*   et = (const int*)  d_in[2];
    const float* wf = (const float*)d_in[3];
    const float* wb = (const float*)d_in[4];
    const float* lw = (const float*)d_in[5];
    const float* lb = (const float*)d_in[6];
    float* out = (float*)d_out;

    const int E = in_sizes[2];
    const int N = in_sizes[0] / 64;
    const int maxC = ((E + 63) >> 6) + NREL;

    char* p = (char*)d_ws;
    unsigned short* wtb = (unsigned short*)p;  p += (size_t)2 * NREL * 4096 * sizeof(unsigned short);
    float* cntf = (float*)p;                   p += (size_t)N * sizeof(float);
    float* cntb = (float*)p;                   p += (size_t)N * sizeof(float);
    int*   hist = (int*)p;                     p += NREL * sizeof(int);
    int*   fill = (int*)p;                     p += NREL * sizeof(int);
    int*   sorted = (int*)p;                   p += (size_t)maxC * 64 * sizeof(int);

    const int* srcp = ei;
    const int* dstp = ei + E;

    // zero cntf, cntb, hist, fill (contiguous)
    hipMemsetAsync(cntf, 0, ((size_t)2 * N + 2 * NREL) * sizeof(float), stream);

    const int nCountB = (E + 255) / 256;
    const int nLinB   = (N + 31) / 32;
    setup_kernel<<<nCountB + 64 + nLinB, 256, 0, stream>>>(
        x, srcp, dstp, et, wf, wb, lw, lb, cntf, cntb, hist, wtb, out, E, N, nCountB);
    scatter_kernel<<<(E + 255) / 256, 256, 0, stream>>>(et, fill, hist, sorted, E);
    dim3 cgrid(maxC, 2);
    conv_mfma<<<cgrid, 256, 0, stream>>>(x, srcp, dstp, cntf, cntb, hist, wtb, sorted, out);
}

// Round 5
// 114.965 us; speedup vs baseline: 2.5806x; 1.0020x over previous
//
#include <hip/hip_runtime.h>

#define NREL 32

typedef short short8 __attribute__((ext_vector_type(8)));
typedef float f32x4 __attribute__((ext_vector_type(4)));

__device__ inline unsigned short f2bf(float f) {
    union { float f; unsigned u; } u; u.f = f;
    unsigned r = u.u + 0x7FFF + ((u.u >> 16) & 1);   // RNE
    return (unsigned short)(r >> 16);
}

// Padded-bucket exclusive scan over hist[32], in-register (lanes 0..31 valid).
__device__ inline void bucket_scan(const int* __restrict__ hist, int lane,
                                   int& h, int& P, int& excl) {
    h = (lane < NREL) ? hist[lane] : 0;
    P = ((h + 63) >> 6) << 6;
    int s = P;
    #pragma unroll
    for (int off = 1; off < 32; off <<= 1) {
        int t = __shfl_up(s, off, 64);
        if ((lane & 31) >= off) s += t;
    }
    excl = s - P;
}

// ---------------------------------------------------------------------------
// ws layout:
//   wtb   [2*32*4096] ushort  bf16 normalized tables, TRANSPOSED:
//                             wtb[(dir*32+r)*4096 + o*64 + i]
//   xbf   [N*64] ushort       bf16(x) (un-scaled; 1/deg applied at epilogue)
//   cntf  [N] float           # edges with src==n
//   cntb  [N] float           # edges with dst==n
//   hist  [32] int            per-rel edge count
//   fill  [32] int            scatter cursors
//   einfo [maxC*64] int4      {src, dst, invf_bits, invb_bits} grouped by rel
// ---------------------------------------------------------------------------

// Fused independent setup: blocks [0,nCountB) count degrees+hist,
// [nCountB,nCountB+64) normalize+transpose weights, rest do x@lin_w^T+b + xbf.
__global__ __launch_bounds__(256) void setup_kernel(
        const float* __restrict__ x,
        const int* __restrict__ src, const int* __restrict__ dst,
        const int* __restrict__ et,
        const float* __restrict__ wf, const float* __restrict__ wb,
        const float* __restrict__ lw, const float* __restrict__ lb,
        float* __restrict__ cntf, float* __restrict__ cntb,
        int* __restrict__ hist, unsigned short* __restrict__ wtb,
        unsigned short* __restrict__ xbf,
        float* __restrict__ out, int E, int N, int nCountB) {
    __shared__ float smem[4 * 8 * 64 + 8];
    int tid = threadIdx.x;
    int b = blockIdx.x;

    if (b < nCountB) {
        // ---- count role ----
        int* lh = (int*)smem;
        if (tid < NREL) lh[tid] = 0;
        __syncthreads();
        int e = b * 256 + tid;
        if (e < E) {
            atomicAdd(&cntf[src[e]], 1.0f);
            atomicAdd(&cntb[dst[e]], 1.0f);
            atomicAdd(&lh[et[e]], 1);
        }
        __syncthreads();
        if (tid < NREL && lh[tid]) atomicAdd(&hist[tid], lh[tid]);
        return;
    }
    b -= nCountB;
    if (b < 64) {
        // ---- norm role: normalize fp32 table row, write bf16 transposed ----
        int rel = b & 31, tab = b >> 5;
        const float* s_ = (tab ? wb : wf) + rel * 4096;
        unsigned short* d_ = wtb + (size_t)b * 4096;
        float* part = smem;
        float ssum = 0.f;
        #pragma unroll
        for (int k = 0; k < 16; k += 4) {
            float4 v = *(const float4*)(s_ + tid * 16 + k);
            ssum += v.x * v.x + v.y * v.y + v.z * v.z + v.w * v.w;
        }
        #pragma unroll
        for (int off = 32; off >= 1; off >>= 1) ssum += __shfl_down(ssum, off, 64);
        if ((tid & 63) == 0) part[tid >> 6] = ssum;
        __syncthreads();
        if (tid == 0) part[4] = 1.0f / (sqrtf(part[0] + part[1] + part[2] + part[3]) + 0.01f);
        __syncthreads();
        float sc = part[4];
        int i = tid >> 2, o0 = (tid & 3) * 16;
        #pragma unroll
        for (int q = 0; q < 4; ++q) {
            float4 v = *(const float4*)(s_ + i * 64 + o0 + q * 4);
            d_[(o0 + q * 4 + 0) * 64 + i] = f2bf(v.x * sc);
            d_[(o0 + q * 4 + 1) * 64 + i] = f2bf(v.y * sc);
            d_[(o0 + q * 4 + 2) * 64 + i] = f2bf(v.z * sc);
            d_[(o0 + q * 4 + 3) * 64 + i] = f2bf(v.w * sc);
        }
        return;
    }
    b -= 64;
    // ---- linear + xbf role: 32 nodes/block ----
    {
        int lane = tid & 63, w = tid >> 6;
        int nodeBase = b * 32 + w * 8;
        float4 wrow[16];
        const float4* lwrow = (const float4*)(lw + lane * 64);
        #pragma unroll
        for (int g = 0; g < 16; ++g) wrow[g] = lwrow[g];
        float bias = lb[lane];
        float* xs = smem + w * 8 * 64;
        #pragma unroll
        for (int t = 0; t < 8; ++t) {
            int n = nodeBase + t;
            if (n < N) {
                float v = x[(size_t)n * 64 + lane];
                xs[t * 64 + lane] = v;
                xbf[(size_t)n * 64 + lane] = f2bf(v);
            }
        }
        __syncthreads();
        for (int t = 0; t < 8; ++t) {
            int n = nodeBase + t;
            if (n >= N) break;
            float acc = bias;
            const float4* xr = (const float4*)(xs + t * 64);
            #pragma unroll
            for (int g = 0; g < 16; ++g) {
                float4 xv = xr[g];
                acc = fmaf(xv.x, wrow[g].x, acc);
                acc = fmaf(xv.y, wrow[g].y, acc);
                acc = fmaf(xv.z, wrow[g].z, acc);
                acc = fmaf(xv.w, wrow[g].w, acc);
            }
            out[(size_t)n * 64 + lane] = acc;
        }
    }
}

// Block-aggregated counting-sort scatter; prefolds {s, d, invf, invb} per edge.
__global__ void scatter_kernel(const int* __restrict__ src, const int* __restrict__ dst,
                               const int* __restrict__ et,
                               const float* __restrict__ cntf, const float* __restrict__ cntb,
                               int* __restrict__ fill, const int* __restrict__ hist,
                               int4* __restrict__ einfo, int E) {
    __shared__ int lh[NREL];
    __shared__ int lbase[NREL];
    __shared__ int bstartS[NREL];
    int tid = threadIdx.x;
    if (tid < 64) {
        int h, P, excl;
        bucket_scan(hist, tid, h, P, excl);
        if (tid < NREL) bstartS[tid] = excl;
    }
    if (tid < NREL) lh[tid] = 0;
    __syncthreads();
    int e = blockIdx.x * blockDim.x + tid;
    int r = 0, my = 0;
    bool valid = (e < E);
    if (valid) { r = et[e]; my = atomicAdd(&lh[r], 1); }
    __syncthreads();
    if (tid < NREL && lh[tid]) lbase[tid] = atomicAdd(&fill[tid], lh[tid]);
    __syncthreads();
    if (valid) {
        int s = src[e], d = dst[e];
        float invf = 1.0f / (cntf[s] + 1.0f);
        float invb = 1.0f / (cntb[d] + 1.0f);
        einfo[bstartS[r] + lbase[r] + my] =
            make_int4(s, d, __float_as_int(invf), __float_as_int(invb));
    }
}

// One block per (64-edge chunk) x (direction = blockIdx.y).
#define APITCH 72  // 64 + 8 shorts pad
__global__ __launch_bounds__(256) void conv_mfma(
        const unsigned short* __restrict__ xbf,
        const int* __restrict__ hist,
        const unsigned short* __restrict__ wtb,
        const int4* __restrict__ einfo,
        float* __restrict__ out) {
    int tid = threadIdx.x;
    int lane = tid & 63;
    int h, P, excl;
    bucket_scan(hist, lane, h, P, excl);
    int pos = blockIdx.x * 64;
    unsigned long long m_ = __ballot(lane < NREL && pos >= excl && pos < excl + P);
    if (m_ == 0) return;
    int rel = __ffsll(m_) - 1;
    int start = __shfl(excl, rel, 64);
    int hr = __shfl(h, rel, 64);
    int valid = hr - (pos - start);
    if (valid > 64) valid = 64;
    int dir = blockIdx.y;

    __shared__ unsigned short As[64 * APITCH];  // As[j][i] = bf16(x[s_j][i])
    __shared__ unsigned short Bs[64 * APITCH];  // Bs[o][i] = Wn[i][o]
    __shared__ int dstS[64];
    __shared__ float invS[64];

    int j = tid >> 2, part = tid & 3;

    // stage B (transposed table is a straight copy)
    {
        const uint4* s4 = (const uint4*)(wtb + (size_t)((dir << 5) + rel) * 4096 + j * 64 + part * 16);
        uint4 v0 = s4[0], v1 = s4[1];
        *(uint4*)(&Bs[j * APITCH + part * 16]) = v0;
        *(uint4*)(&Bs[j * APITCH + part * 16 + 8]) = v1;
    }

    // stage A: pure bf16 row copy (deg scaling moved to epilogue)
    if (j >= valid) {
        uint4 z = {0, 0, 0, 0};
        *(uint4*)(&As[j * APITCH + part * 16]) = z;
        *(uint4*)(&As[j * APITCH + part * 16 + 8]) = z;
        if (part == 0) { dstS[j] = -1; invS[j] = 0.f; }
    } else {
        int4 v = einfo[pos + j];
        int s_ = dir ? v.y : v.x;
        int d_ = dir ? v.x : v.y;
        float inv = __int_as_float(dir ? v.w : v.z);
        const uint4* xr = (const uint4*)(xbf + (size_t)s_ * 64);
        uint4 a0 = xr[part * 2], a1 = xr[part * 2 + 1];
        *(uint4*)(&As[j * APITCH + part * 16]) = a0;
        *(uint4*)(&As[j * APITCH + part * 16 + 8]) = a1;
        if (part == 0) { dstS[j] = d_; invS[j] = inv; }
    }
    __syncthreads();

    // MFMA: wave w computes edge rows [16w,16w+16) x all 64 out channels
    int w = tid >> 6;
    int m = lane & 15, quad = lane >> 4;
    f32x4 acc0 = {0.f, 0.f, 0.f, 0.f}, acc1 = acc0, acc2 = acc0, acc3 = acc0;
    #pragma unroll
    for (int k0 = 0; k0 < 64; k0 += 32) {
        short8 a  = *(const short8*)(&As[(w * 16 + m) * APITCH + k0 + quad * 8]);
        short8 b0 = *(const short8*)(&Bs[(0  + m) * APITCH + k0 + quad * 8]);
        short8 b1 = *(const short8*)(&Bs[(16 + m) * APITCH + k0 + quad * 8]);
        short8 b2 = *(const short8*)(&Bs[(32 + m) * APITCH + k0 + quad * 8]);
        short8 b3 = *(const short8*)(&Bs[(48 + m) * APITCH + k0 + quad * 8]);
        acc0 = __builtin_amdgcn_mfma_f32_16x16x32_bf16(a, b0, acc0, 0, 0, 0);
        acc1 = __builtin_amdgcn_mfma_f32_16x16x32_bf16(a, b1, acc1, 0, 0, 0);
        acc2 = __builtin_amdgcn_mfma_f32_16x16x32_bf16(a, b2, acc2, 0, 0, 0);
        acc3 = __builtin_amdgcn_mfma_f32_16x16x32_bf16(a, b3, acc3, 0, 0, 0);
    }

    // epilogue: C/D layout col=lane&15, row=quad*4+reg; scale by 1/deg in fp32
    int row_base = w * 16 + quad * 4;
    #pragma unroll
    for (int r = 0; r < 4; ++r) {
        int row = row_base + r;
        int d_ = dstS[row];
        if (d_ >= 0) {
            float inv = invS[row];
            float* op = out + (size_t)d_ * 64 + m;
            atomicAdd(op +  0, acc0[r] * inv);
            atomicAdd(op + 16, acc1[r] * inv);
            atomicAdd(op + 32, acc2[r] * inv);
            atomicAdd(op + 48, acc3[r] * inv);
        }
    }
}

extern "C" void kernel_launch(void* const* d_in, const int* in_sizes, int n_in,
                              void* d_out, int out_size, void* d_ws, size_t ws_size,
                              hipStream_t stream) {
    const float* x  = (const float*)d_in[0];
    const int*   ei = (const int*)  d_in[1];
    const int*   et = (const int*)  d_in[2];
    const float* wf = (const float*)d_in[3];
    const float* wb = (const float*)d_in[4];
    const float* lw = (const float*)d_in[5];
    const float* lb = (const float*)d_in[6];
    float* out = (float*)d_out;

    const int E = in_sizes[2];
    const int N = in_sizes[0] / 64;
    const int maxC = ((E + 63) >> 6) + NREL;

    char* p = (char*)d_ws;
    unsigned short* wtb = (unsigned short*)p;  p += (size_t)2 * NREL * 4096 * sizeof(unsigned short);
    unsigned short* xbf = (unsigned short*)p;  p += (size_t)N * 64 * sizeof(unsigned short);
    float* cntf = (float*)p;                   p += (size_t)N * sizeof(float);
    float* cntb = (float*)p;                   p += (size_t)N * sizeof(float);
    int*   hist = (int*)p;                     p += NREL * sizeof(int);
    int*   fill = (int*)p;                     p += NREL * sizeof(int);
    int4*  einfo = (int4*)p;                   p += (size_t)maxC * 64 * sizeof(int4);

    const int* srcp = ei;
    const int* dstp = ei + E;

    // zero cntf, cntb, hist, fill (contiguous)
    hipMemsetAsync(cntf, 0, ((size_t)2 * N + 2 * NREL) * sizeof(float), stream);

    const int nCountB = (E + 255) / 256;
    const int nLinB   = (N + 31) / 32;
    setup_kernel<<<nCountB + 64 + nLinB, 256, 0, stream>>>(
        x, srcp, dstp, et, wf, wb, lw, lb, cntf, cntb, hist, wtb, xbf, out, E, N, nCountB);
    scatter_kernel<<<(E + 255) / 256, 256, 0, stream>>>(
        srcp, dstp, et, cntf, cntb, fill, hist, einfo, E);
    dim3 cgrid(maxC, 2);
    conv_mfma<<<cgrid, 256, 0, stream>>>(xbf, hist, wtb, einfo, out);
}